// Round 1
// baseline (284.568 us; speedup 1.0000x reference)
//
#include <hip/hip_runtime.h>
#include <math.h>

static constexpr int B_ = 16, NA_ = 3, CH = 85, NCLS = 80;
static constexpr int G0 = 80, G1 = 40, G2 = 20;
static constexpr int N0 = 4096, N1 = 2048, N2 = 1024;
static constexpr int C0 = B_ * NA_ * G0 * G0;   // 307200
static constexpr int C1 = B_ * NA_ * G1 * G1;   // 76800
static constexpr int C2 = B_ * NA_ * G2 * G2;   // 19200
static constexpr int TC = C0 + C1 + C2;         // 403200
static constexpr int OBJ_BLOCKS = TC / 256;     // 1575 (all level-pure: C0,C1,C2 % 256 == 0)
static constexpr int TGT_BLOCKS = (N0 + N1 + N2) / 256;  // 28 (level-pure too)
static constexpr int TOTAL_BLOCKS = OBJ_BLOCKS + TGT_BLOCKS;

struct Params {
    const float* p[3];
    const float* tbox[3];
    const float* anch[3];
    const int* bb[3];
    const int* aa[3];
    const int* gj[3];
    const int* gi[3];
    const int* tcls[3];
};

__device__ __forceinline__ float softplusf(float x) {
    // logaddexp(0, x), numerically stable
    return fmaxf(x, 0.0f) + log1pf(expf(-fabsf(x)));
}
__device__ __forceinline__ float sigm(float x) { return 1.0f / (1.0f + expf(-x)); }

// acc layout (doubles): [lvl*4+0]=obj softplus sum, +1 = sum x*t (scatter corr),
//                       +2 = sum(1-ciou), +3 = cls bce numerator sum
__global__ __launch_bounds__(256) void crit_main(Params P, double* acc,
                                                 unsigned int* done, float* out) {
    __shared__ float sh[12];
    const int tid = threadIdx.x;
    const int blk = blockIdx.x;

    if (blk < OBJ_BLOCKS) {
        // ---- whole-grid objectness softplus: one cell per thread, stride-85 channel 4
        int t = blk * 256 + tid;
        int lvl, c;
        if (t < C0)            { lvl = 0; c = t; }
        else if (t < C0 + C1)  { lvl = 1; c = t - C0; }
        else                   { lvl = 2; c = t - C0 - C1; }
        float v = softplusf(P.p[lvl][c * CH + 4]);
        #pragma unroll
        for (int off = 32; off > 0; off >>= 1) v += __shfl_down(v, off, 64);
        if ((tid & 63) == 0) sh[tid >> 6] = v;
        __syncthreads();
        if (tid == 0) {
            double s = (double)sh[0] + (double)sh[1] + (double)sh[2] + (double)sh[3];
            atomicAdd(&acc[lvl * 4 + 0], s);
        }
    } else {
        // ---- per-target: gather row, CIoU, obj correction, class BCE
        int t = (blk - OBJ_BLOCKS) * 256 + tid;
        int lvl, k, g;
        if (t < N0)            { lvl = 0; k = t;            g = G0; }
        else if (t < N0 + N1)  { lvl = 1; k = t - N0;       g = G1; }
        else                   { lvl = 2; k = t - N0 - N1;  g = G2; }

        const int bi = P.bb[lvl][k], ai = P.aa[lvl][k];
        const int gjj = P.gj[lvl][k], gii = P.gi[lvl][k];
        const int tc = P.tcls[lvl][k];
        const float* ps = P.p[lvl] + ((((long long)bi * NA_ + ai) * g + gjj) * g + gii) * CH;

        const float s0 = ps[0], s1 = ps[1], s2 = ps[2], s3 = ps[3], s4 = ps[4];
        const float ax = P.anch[lvl][k * 2 + 0], ay = P.anch[lvl][k * 2 + 1];
        const float tx = P.tbox[lvl][k * 4 + 0], ty = P.tbox[lvl][k * 4 + 1];
        const float tw = P.tbox[lvl][k * 4 + 2], th = P.tbox[lvl][k * 4 + 3];

        const float eps = 1e-7f;
        const float x1 = sigm(s0) * 2.0f - 0.5f;
        const float y1 = sigm(s1) * 2.0f - 0.5f;
        const float swv = sigm(s2) * 2.0f;  const float w1 = swv * swv * ax;
        const float shv = sigm(s3) * 2.0f;  const float h1 = shv * shv * ay;

        const float b1x1 = x1 - w1 * 0.5f, b1x2 = x1 + w1 * 0.5f;
        const float b1y1 = y1 - h1 * 0.5f, b1y2 = y1 + h1 * 0.5f;
        const float b2x1 = tx - tw * 0.5f, b2x2 = tx + tw * 0.5f;
        const float b2y1 = ty - th * 0.5f, b2y2 = ty + th * 0.5f;

        const float iw = fmaxf(fminf(b1x2, b2x2) - fmaxf(b1x1, b2x1), 0.0f);
        const float ih = fmaxf(fminf(b1y2, b2y2) - fmaxf(b1y1, b2y1), 0.0f);
        const float inter = iw * ih;
        const float uni = w1 * h1 + tw * th - inter + eps;
        const float iou = inter / uni;
        const float cw = fmaxf(b1x2, b2x2) - fminf(b1x1, b2x1);
        const float chh = fmaxf(b1y2, b2y2) - fminf(b1y1, b2y1);
        const float c2 = cw * cw + chh * chh + eps;
        const float dx = b2x1 + b2x2 - b1x1 - b1x2;
        const float dy = b2y1 + b2y2 - b1y1 - b1y2;
        const float rho2 = (dx * dx + dy * dy) * 0.25f;
        const float dv = atanf(tw / (th + eps)) - atanf(w1 / (h1 + eps));
        const float v4 = 0.40528473456935109f * dv * dv;   // 4/pi^2
        const float alpha = v4 / (v4 - iou + 1.0f + eps);
        const float ciou = iou - (rho2 / c2 + v4 * alpha);

        float boxv = 1.0f - ciou;
        float xtv  = s4 * fmaxf(ciou, 0.0f);
        float clsv = 0.0f;
        #pragma unroll 8
        for (int c = 0; c < NCLS; ++c) clsv += softplusf(ps[5 + c]);
        clsv -= ps[5 + tc];

        #pragma unroll
        for (int off = 32; off > 0; off >>= 1) {
            boxv += __shfl_down(boxv, off, 64);
            xtv  += __shfl_down(xtv,  off, 64);
            clsv += __shfl_down(clsv, off, 64);
        }
        const int wid = tid >> 6;
        if ((tid & 63) == 0) { sh[wid * 3 + 0] = boxv; sh[wid * 3 + 1] = xtv; sh[wid * 3 + 2] = clsv; }
        __syncthreads();
        if (tid == 0) {
            double bs = 0, xs = 0, cs = 0;
            #pragma unroll
            for (int w = 0; w < 4; ++w) {
                bs += (double)sh[w * 3 + 0];
                xs += (double)sh[w * 3 + 1];
                cs += (double)sh[w * 3 + 2];
            }
            atomicAdd(&acc[lvl * 4 + 2], bs);
            atomicAdd(&acc[lvl * 4 + 1], xs);
            atomicAdd(&acc[lvl * 4 + 3], cs);
        }
    }

    // ---- last block finalizes
    __syncthreads();
    if (tid == 0) {
        __threadfence();
        unsigned int old = atomicAdd(done, 1u);
        if (old == (unsigned int)(TOTAL_BLOCKS - 1)) {
            __threadfence();
            const double bal[3]   = {4.0, 1.0, 0.4};
            const double ncell[3] = {(double)C0, (double)C1, (double)C2};
            const double nt[3]    = {(double)N0, (double)N1, (double)N2};
            double lbox = 0.0, lobj = 0.0, lcls = 0.0;
            for (int l = 0; l < 3; ++l) {
                // coherent (device-scope) reads of cross-XCD accumulators
                double sp = atomicAdd(&acc[l * 4 + 0], 0.0);
                double xt = atomicAdd(&acc[l * 4 + 1], 0.0);
                double bx = atomicAdd(&acc[l * 4 + 2], 0.0);
                double cl = atomicAdd(&acc[l * 4 + 3], 0.0);
                lbox += bx / nt[l];
                lobj += bal[l] * (sp - xt) / ncell[l];
                lcls += cl / (nt[l] * (double)NCLS);
            }
            lbox *= 0.05;   // W_BOX
            lcls *= 0.5;    // W_CLS
            const double loss = lbox + lobj + lcls;
            out[0] = (float)(loss * (double)B_);
            out[1] = (float)lbox;
            out[2] = (float)lobj;
            out[3] = (float)lcls;
            out[4] = (float)loss;
        }
    }
}

extern "C" void kernel_launch(void* const* d_in, const int* in_sizes, int n_in,
                              void* d_out, int out_size, void* d_ws, size_t ws_size,
                              hipStream_t stream) {
    Params P;
    for (int l = 0; l < 3; ++l) {
        void* const* base = d_in + l * 8;  // dict order: p, tbox, anch, b, a, gj, gi, tcls
        P.p[l]    = (const float*)base[0];
        P.tbox[l] = (const float*)base[1];
        P.anch[l] = (const float*)base[2];
        P.bb[l]   = (const int*)base[3];
        P.aa[l]   = (const int*)base[4];
        P.gj[l]   = (const int*)base[5];
        P.gi[l]   = (const int*)base[6];
        P.tcls[l] = (const int*)base[7];
    }
    double* acc = (double*)d_ws;
    unsigned int* done = (unsigned int*)((char*)d_ws + 12 * sizeof(double));
    hipMemsetAsync(d_ws, 0, 128, stream);
    crit_main<<<TOTAL_BLOCKS, 256, 0, stream>>>(P, acc, done, (float*)d_out);
}

// Round 2
// 227.575 us; speedup vs baseline: 1.2504x; 1.2504x over previous
//
#include <hip/hip_runtime.h>
#include <math.h>

static constexpr int B_ = 16, NA_ = 3, CH = 85, NCLS = 80;
static constexpr int G0 = 80, G1 = 40, G2 = 20;
static constexpr int N0 = 4096, N1 = 2048, N2 = 1024;
static constexpr int C0 = B_ * NA_ * G0 * G0;   // 307200
static constexpr int C1 = B_ * NA_ * G1 * G1;   // 76800
static constexpr int C2 = B_ * NA_ * G2 * G2;   // 19200

// Level-pure block layout (no bounds checks anywhere):
//  L0 obj: 300 blocks x 256 thr x 4 cells = 307200
//  L1 obj:  75 blocks x 256 thr x 4 cells =  76800
//  L2 obj:  25 blocks x 256 thr x 3 cells =  19200
//  targets: 16 + 8 + 4 blocks, 1 target/thread
static constexpr int OB0 = 300, OB1 = 75, OB2 = 25;
static constexpr int OBJ_BLOCKS = OB0 + OB1 + OB2;            // 400
static constexpr int TGT_BLOCKS = (N0 + N1 + N2) / 256;       // 28
static constexpr int TOTAL_BLOCKS = OBJ_BLOCKS + TGT_BLOCKS;  // 428

static constexpr int NSLOT = 16;   // acc[slot][12] doubles, slot-major (96B apart)

struct Params {
    const float* p[3];
    const float* tbox[3];
    const float* anch[3];
    const int* bb[3];
    const int* aa[3];
    const int* gj[3];
    const int* gi[3];
    const int* tcls[3];
};

__device__ __forceinline__ float softplusf(float x) {
    return fmaxf(x, 0.0f) + log1pf(expf(-fabsf(x)));
}
__device__ __forceinline__ float sigm(float x) { return 1.0f / (1.0f + expf(-x)); }

// quantity q per level: 0 = obj softplus sum, 1 = sum s4*clip(ciou) (scatter corr),
//                       2 = sum(1-ciou), 3 = cls bce numerator
__global__ __launch_bounds__(256) void crit_main(Params P, double* acc) {
    __shared__ float sh[12];
    const int tid = threadIdx.x;
    const int blk = blockIdx.x;
    const int slot = blk & (NSLOT - 1);

    if (blk < OBJ_BLOCKS) {
        int lvl, gidL, T, nk;
        if (blk < OB0)            { lvl = 0; gidL = blk * 256 + tid;          T = OB0 * 256; nk = 4; }
        else if (blk < OB0 + OB1) { lvl = 1; gidL = (blk - OB0) * 256 + tid;  T = OB1 * 256; nk = 4; }
        else                      { lvl = 2; gidL = (blk - OB0 - OB1) * 256 + tid; T = OB2 * 256; nk = 3; }
        const float* p = P.p[lvl];
        // batch independent loads, then compute
        float x[4];
        #pragma unroll
        for (int k = 0; k < 4; ++k)
            if (k < nk) x[k] = p[(long long)(gidL + k * T) * CH + 4];
        float v = 0.0f;
        #pragma unroll
        for (int k = 0; k < 4; ++k)
            if (k < nk) v += softplusf(x[k]);
        #pragma unroll
        for (int off = 32; off > 0; off >>= 1) v += __shfl_down(v, off, 64);
        if ((tid & 63) == 0) sh[tid >> 6] = v;
        __syncthreads();
        if (tid == 0) {
            double s = (double)sh[0] + (double)sh[1] + (double)sh[2] + (double)sh[3];
            atomicAdd(&acc[slot * 12 + lvl * 4 + 0], s);
        }
    } else {
        const int t = (blk - OBJ_BLOCKS) * 256 + tid;
        int lvl, k, g;
        if (t < N0)            { lvl = 0; k = t;            g = G0; }
        else if (t < N0 + N1)  { lvl = 1; k = t - N0;       g = G1; }
        else                   { lvl = 2; k = t - N0 - N1;  g = G2; }

        const int bi = P.bb[lvl][k], ai = P.aa[lvl][k];
        const int gjj = P.gj[lvl][k], gii = P.gi[lvl][k];
        const int tc = P.tcls[lvl][k];
        const float* ps = P.p[lvl] + ((((long long)bi * NA_ + ai) * g + gjj) * g + gii) * CH;

        const float s0 = ps[0], s1 = ps[1], s2 = ps[2], s3 = ps[3], s4 = ps[4];
        const float ax = P.anch[lvl][k * 2 + 0], ay = P.anch[lvl][k * 2 + 1];
        const float tx = P.tbox[lvl][k * 4 + 0], ty = P.tbox[lvl][k * 4 + 1];
        const float tw = P.tbox[lvl][k * 4 + 2], th = P.tbox[lvl][k * 4 + 3];

        const float eps = 1e-7f;
        const float x1 = sigm(s0) * 2.0f - 0.5f;
        const float y1 = sigm(s1) * 2.0f - 0.5f;
        const float swv = sigm(s2) * 2.0f;  const float w1 = swv * swv * ax;
        const float shv = sigm(s3) * 2.0f;  const float h1 = shv * shv * ay;

        const float b1x1 = x1 - w1 * 0.5f, b1x2 = x1 + w1 * 0.5f;
        const float b1y1 = y1 - h1 * 0.5f, b1y2 = y1 + h1 * 0.5f;
        const float b2x1 = tx - tw * 0.5f, b2x2 = tx + tw * 0.5f;
        const float b2y1 = ty - th * 0.5f, b2y2 = ty + th * 0.5f;

        const float iw = fmaxf(fminf(b1x2, b2x2) - fmaxf(b1x1, b2x1), 0.0f);
        const float ih = fmaxf(fminf(b1y2, b2y2) - fmaxf(b1y1, b2y1), 0.0f);
        const float inter = iw * ih;
        const float uni = w1 * h1 + tw * th - inter + eps;
        const float iou = inter / uni;
        const float cw = fmaxf(b1x2, b2x2) - fminf(b1x1, b2x1);
        const float chh = fmaxf(b1y2, b2y2) - fminf(b1y1, b2y1);
        const float c2 = cw * cw + chh * chh + eps;
        const float dx = b2x1 + b2x2 - b1x1 - b1x2;
        const float dy = b2y1 + b2y2 - b1y1 - b1y2;
        const float rho2 = (dx * dx + dy * dy) * 0.25f;
        const float dv = atanf(tw / (th + eps)) - atanf(w1 / (h1 + eps));
        const float v4 = 0.40528473456935109f * dv * dv;   // 4/pi^2
        const float alpha = v4 / (v4 - iou + 1.0f + eps);
        const float ciou = iou - (rho2 / c2 + v4 * alpha);

        float boxv = 1.0f - ciou;
        float xtv  = s4 * fmaxf(ciou, 0.0f);
        float clsv = 0.0f;
        #pragma unroll 8
        for (int c = 0; c < NCLS; ++c) clsv += softplusf(ps[5 + c]);
        clsv -= ps[5 + tc];

        #pragma unroll
        for (int off = 32; off > 0; off >>= 1) {
            boxv += __shfl_down(boxv, off, 64);
            xtv  += __shfl_down(xtv,  off, 64);
            clsv += __shfl_down(clsv, off, 64);
        }
        const int wid = tid >> 6;
        if ((tid & 63) == 0) { sh[wid * 3 + 0] = boxv; sh[wid * 3 + 1] = xtv; sh[wid * 3 + 2] = clsv; }
        __syncthreads();
        if (tid == 0) {
            double bs = 0, xs = 0, cs = 0;
            #pragma unroll
            for (int w = 0; w < 4; ++w) {
                bs += (double)sh[w * 3 + 0];
                xs += (double)sh[w * 3 + 1];
                cs += (double)sh[w * 3 + 2];
            }
            atomicAdd(&acc[slot * 12 + lvl * 4 + 1], xs);
            atomicAdd(&acc[slot * 12 + lvl * 4 + 2], bs);
            atomicAdd(&acc[slot * 12 + lvl * 4 + 3], cs);
        }
    }
}

__global__ __launch_bounds__(256) void crit_finalize(const double* acc, float* out) {
    __shared__ double sh[NSLOT * 12];
    const int tid = threadIdx.x;
    if (tid < NSLOT * 12) sh[tid] = acc[tid];
    __syncthreads();
    if (tid == 0) {
        double q[12];
        #pragma unroll
        for (int i = 0; i < 12; ++i) {
            double s = 0.0;
            for (int sl = 0; sl < NSLOT; ++sl) s += sh[sl * 12 + i];
            q[i] = s;
        }
        const double bal[3]   = {4.0, 1.0, 0.4};
        const double ncell[3] = {(double)C0, (double)C1, (double)C2};
        const double nt[3]    = {(double)N0, (double)N1, (double)N2};
        double lbox = 0.0, lobj = 0.0, lcls = 0.0;
        for (int l = 0; l < 3; ++l) {
            lobj += bal[l] * (q[l * 4 + 0] - q[l * 4 + 1]) / ncell[l];
            lbox += q[l * 4 + 2] / nt[l];
            lcls += q[l * 4 + 3] / (nt[l] * (double)NCLS);
        }
        lbox *= 0.05;   // W_BOX
        lcls *= 0.5;    // W_CLS
        const double loss = lbox + lobj + lcls;
        out[0] = (float)(loss * (double)B_);
        out[1] = (float)lbox;
        out[2] = (float)lobj;
        out[3] = (float)lcls;
        out[4] = (float)loss;
    }
}

extern "C" void kernel_launch(void* const* d_in, const int* in_sizes, int n_in,
                              void* d_out, int out_size, void* d_ws, size_t ws_size,
                              hipStream_t stream) {
    Params P;
    for (int l = 0; l < 3; ++l) {
        void* const* base = d_in + l * 8;  // dict order: p, tbox, anch, b, a, gj, gi, tcls
        P.p[l]    = (const float*)base[0];
        P.tbox[l] = (const float*)base[1];
        P.anch[l] = (const float*)base[2];
        P.bb[l]   = (const int*)base[3];
        P.aa[l]   = (const int*)base[4];
        P.gj[l]   = (const int*)base[5];
        P.gi[l]   = (const int*)base[6];
        P.tcls[l] = (const int*)base[7];
    }
    double* acc = (double*)d_ws;
    hipMemsetAsync(d_ws, 0, NSLOT * 12 * sizeof(double), stream);
    crit_main<<<TOTAL_BLOCKS, 256, 0, stream>>>(P, acc);
    crit_finalize<<<1, 256, 0, stream>>>(acc, (float*)d_out);
}

// Round 3
// 211.966 us; speedup vs baseline: 1.3425x; 1.0736x over previous
//
#include <hip/hip_runtime.h>
#include <math.h>

static constexpr int B_ = 16, NA_ = 3, CH = 85, NCLS = 80;
static constexpr int G0 = 80, G1 = 40, G2 = 20;
static constexpr int N0 = 4096, N1 = 2048, N2 = 1024;
static constexpr int C0 = B_ * NA_ * G0 * G0;   // 307200
static constexpr int C1 = B_ * NA_ * G1 * G1;   // 76800
static constexpr int C2 = B_ * NA_ * G2 * G2;   // 19200

// Level-pure block layout (no bounds checks anywhere):
//  L0 obj: 300 blocks x 256 thr x 4 cells = 307200
//  L1 obj:  75 blocks x 256 thr x 4 cells =  76800
//  L2 obj:  25 blocks x 256 thr x 3 cells =  19200
//  targets: 4 threads/target, 64 targets/block -> 64 + 32 + 16 = 112 blocks
static constexpr int OB0 = 300, OB1 = 75, OB2 = 25;
static constexpr int OBJ_BLOCKS = OB0 + OB1 + OB2;            // 400
static constexpr int TGT_BLOCKS = (N0 + N1 + N2) / 64;        // 112
static constexpr int TOTAL_BLOCKS = OBJ_BLOCKS + TGT_BLOCKS;  // 512

static constexpr int NSLOT = 16;   // acc[slot][12] doubles

struct Params {
    const float* p[3];
    const float* tbox[3];
    const float* anch[3];
    const int* bb[3];
    const int* aa[3];
    const int* gj[3];
    const int* gi[3];
    const int* tcls[3];
};

__device__ __forceinline__ float softplusf(float x) {
    return fmaxf(x, 0.0f) + log1pf(expf(-fabsf(x)));
}
__device__ __forceinline__ float sigm(float x) { return 1.0f / (1.0f + expf(-x)); }

// quantity q per level: 0 = obj softplus sum, 1 = sum s4*clip(ciou) (scatter corr),
//                       2 = sum(1-ciou), 3 = cls bce numerator
__global__ __launch_bounds__(256) void crit_main(Params P, double* acc) {
    __shared__ float sh[12];
    const int tid = threadIdx.x;
    const int blk = blockIdx.x;
    const int slot = blk & (NSLOT - 1);

    if (blk < OBJ_BLOCKS) {
        int lvl, gidL, T, nk;
        if (blk < OB0)            { lvl = 0; gidL = blk * 256 + tid;          T = OB0 * 256; nk = 4; }
        else if (blk < OB0 + OB1) { lvl = 1; gidL = (blk - OB0) * 256 + tid;  T = OB1 * 256; nk = 4; }
        else                      { lvl = 2; gidL = (blk - OB0 - OB1) * 256 + tid; T = OB2 * 256; nk = 3; }
        const float* p = P.p[lvl];
        float x[4];
        #pragma unroll
        for (int k = 0; k < 4; ++k)
            if (k < nk) x[k] = p[(long long)(gidL + k * T) * CH + 4];
        float v = 0.0f;
        #pragma unroll
        for (int k = 0; k < 4; ++k)
            if (k < nk) v += softplusf(x[k]);
        #pragma unroll
        for (int off = 32; off > 0; off >>= 1) v += __shfl_down(v, off, 64);
        if ((tid & 63) == 0) sh[tid >> 6] = v;
        __syncthreads();
        if (tid == 0) {
            double s = (double)sh[0] + (double)sh[1] + (double)sh[2] + (double)sh[3];
            atomicAdd(&acc[slot * 12 + lvl * 4 + 0], s);
        }
    } else {
        // ---- 4 threads per target, 64 targets per block (level-pure blocks)
        const int t = (blk - OBJ_BLOCKS) * 64 + (tid >> 2);  // global target id
        const int j = tid & 3;                               // sub-lane within target
        int lvl, k, g;
        if (t < N0)            { lvl = 0; k = t;            g = G0; }
        else if (t < N0 + N1)  { lvl = 1; k = t - N0;       g = G1; }
        else                   { lvl = 2; k = t - N0 - N1;  g = G2; }

        const int bi = P.bb[lvl][k], ai = P.aa[lvl][k];
        const int gjj = P.gj[lvl][k], gii = P.gi[lvl][k];
        const int tc = P.tcls[lvl][k];
        const float* ps = P.p[lvl] + ((((long long)bi * NA_ + ai) * g + gjj) * g + gii) * CH;

        // class BCE partial: 20 contiguous classes per thread
        const int cbase = 5 + j * 20;
        float clsv = 0.0f;
        #pragma unroll 5
        for (int c = 0; c < 20; ++c) clsv += softplusf(ps[cbase + c]);
        if (tc >= j * 20 && tc < j * 20 + 20) clsv -= ps[5 + tc];
        // sum class partials across the aligned 4-lane group
        clsv += __shfl_xor(clsv, 1, 64);
        clsv += __shfl_xor(clsv, 2, 64);

        float boxv = 0.0f, xtv = 0.0f;
        if (j == 0) {
            const float s0 = ps[0], s1 = ps[1], s2 = ps[2], s3 = ps[3], s4 = ps[4];
            const float ax = P.anch[lvl][k * 2 + 0], ay = P.anch[lvl][k * 2 + 1];
            const float tx = P.tbox[lvl][k * 4 + 0], ty = P.tbox[lvl][k * 4 + 1];
            const float tw = P.tbox[lvl][k * 4 + 2], th = P.tbox[lvl][k * 4 + 3];

            const float eps = 1e-7f;
            const float x1 = sigm(s0) * 2.0f - 0.5f;
            const float y1 = sigm(s1) * 2.0f - 0.5f;
            const float swv = sigm(s2) * 2.0f;  const float w1 = swv * swv * ax;
            const float shv = sigm(s3) * 2.0f;  const float h1 = shv * shv * ay;

            const float b1x1 = x1 - w1 * 0.5f, b1x2 = x1 + w1 * 0.5f;
            const float b1y1 = y1 - h1 * 0.5f, b1y2 = y1 + h1 * 0.5f;
            const float b2x1 = tx - tw * 0.5f, b2x2 = tx + tw * 0.5f;
            const float b2y1 = ty - th * 0.5f, b2y2 = ty + th * 0.5f;

            const float iw = fmaxf(fminf(b1x2, b2x2) - fmaxf(b1x1, b2x1), 0.0f);
            const float ih = fmaxf(fminf(b1y2, b2y2) - fmaxf(b1y1, b2y1), 0.0f);
            const float inter = iw * ih;
            const float uni = w1 * h1 + tw * th - inter + eps;
            const float iou = inter / uni;
            const float cw = fmaxf(b1x2, b2x2) - fminf(b1x1, b2x1);
            const float chh = fmaxf(b1y2, b2y2) - fminf(b1y1, b2y1);
            const float c2 = cw * cw + chh * chh + eps;
            const float dx = b2x1 + b2x2 - b1x1 - b1x2;
            const float dy = b2y1 + b2y2 - b1y1 - b1y2;
            const float rho2 = (dx * dx + dy * dy) * 0.25f;
            const float dv = atanf(tw / (th + eps)) - atanf(w1 / (h1 + eps));
            const float v4 = 0.40528473456935109f * dv * dv;   // 4/pi^2
            const float alpha = v4 / (v4 - iou + 1.0f + eps);
            const float ciou = iou - (rho2 / c2 + v4 * alpha);

            boxv = 1.0f - ciou;
            xtv  = s4 * fmaxf(ciou, 0.0f);
        } else {
            clsv = 0.0f;   // only group-lane-0 contributes the (full) class sum
        }

        #pragma unroll
        for (int off = 32; off > 0; off >>= 1) {
            boxv += __shfl_down(boxv, off, 64);
            xtv  += __shfl_down(xtv,  off, 64);
            clsv += __shfl_down(clsv, off, 64);
        }
        const int wid = tid >> 6;
        if ((tid & 63) == 0) { sh[wid * 3 + 0] = boxv; sh[wid * 3 + 1] = xtv; sh[wid * 3 + 2] = clsv; }
        __syncthreads();
        if (tid == 0) {
            double bs = 0, xs = 0, cs = 0;
            #pragma unroll
            for (int w = 0; w < 4; ++w) {
                bs += (double)sh[w * 3 + 0];
                xs += (double)sh[w * 3 + 1];
                cs += (double)sh[w * 3 + 2];
            }
            atomicAdd(&acc[slot * 12 + lvl * 4 + 1], xs);
            atomicAdd(&acc[slot * 12 + lvl * 4 + 2], bs);
            atomicAdd(&acc[slot * 12 + lvl * 4 + 3], cs);
        }
    }
}

__global__ __launch_bounds__(256) void crit_finalize(const double* acc, float* out) {
    __shared__ double sh[NSLOT * 12];
    const int tid = threadIdx.x;
    if (tid < NSLOT * 12) sh[tid] = acc[tid];
    __syncthreads();
    if (tid == 0) {
        double q[12];
        #pragma unroll
        for (int i = 0; i < 12; ++i) {
            double s = 0.0;
            for (int sl = 0; sl < NSLOT; ++sl) s += sh[sl * 12 + i];
            q[i] = s;
        }
        const double bal[3]   = {4.0, 1.0, 0.4};
        const double ncell[3] = {(double)C0, (double)C1, (double)C2};
        const double nt[3]    = {(double)N0, (double)N1, (double)N2};
        double lbox = 0.0, lobj = 0.0, lcls = 0.0;
        for (int l = 0; l < 3; ++l) {
            lobj += bal[l] * (q[l * 4 + 0] - q[l * 4 + 1]) / ncell[l];
            lbox += q[l * 4 + 2] / nt[l];
            lcls += q[l * 4 + 3] / (nt[l] * (double)NCLS);
        }
        lbox *= 0.05;   // W_BOX
        lcls *= 0.5;    // W_CLS
        const double loss = lbox + lobj + lcls;
        out[0] = (float)(loss * (double)B_);
        out[1] = (float)lbox;
        out[2] = (float)lobj;
        out[3] = (float)lcls;
        out[4] = (float)loss;
    }
}

extern "C" void kernel_launch(void* const* d_in, const int* in_sizes, int n_in,
                              void* d_out, int out_size, void* d_ws, size_t ws_size,
                              hipStream_t stream) {
    Params P;
    for (int l = 0; l < 3; ++l) {
        void* const* base = d_in + l * 8;  // dict order: p, tbox, anch, b, a, gj, gi, tcls
        P.p[l]    = (const float*)base[0];
        P.tbox[l] = (const float*)base[1];
        P.anch[l] = (const float*)base[2];
        P.bb[l]   = (const int*)base[3];
        P.aa[l]   = (const int*)base[4];
        P.gj[l]   = (const int*)base[5];
        P.gi[l]   = (const int*)base[6];
        P.tcls[l] = (const int*)base[7];
    }
    double* acc = (double*)d_ws;
    hipMemsetAsync(d_ws, 0, NSLOT * 12 * sizeof(double), stream);
    crit_main<<<TOTAL_BLOCKS, 256, 0, stream>>>(P, acc);
    crit_finalize<<<1, 256, 0, stream>>>(acc, (float*)d_out);
}

// Round 4
// 211.702 us; speedup vs baseline: 1.3442x; 1.0012x over previous
//
#include <hip/hip_runtime.h>
#include <math.h>

static constexpr int B_ = 16, NA_ = 3, CH = 85, NCLS = 80;
static constexpr int G0 = 80, G1 = 40, G2 = 20;
static constexpr int N0 = 4096, N1 = 2048, N2 = 1024;
static constexpr int C0 = B_ * NA_ * G0 * G0;   // 307200
static constexpr int C1 = B_ * NA_ * G1 * G1;   // 76800
static constexpr int C2 = B_ * NA_ * G2 * G2;   // 19200

// Level-pure block layout (no bounds checks anywhere):
//  L0 obj: 300 blocks x 256 thr x 4 cells = 307200
//  L1 obj:  75 blocks x 256 thr x 4 cells =  76800
//  L2 obj:  25 blocks x 256 thr x 3 cells =  19200
//  targets: 4 threads/target, 64 targets/block -> 64 + 32 + 16 = 112 blocks
static constexpr int OB0 = 300, OB1 = 75, OB2 = 25;
static constexpr int OBJ_BLOCKS = OB0 + OB1 + OB2;            // 400
static constexpr int TGT_BLOCKS = (N0 + N1 + N2) / 64;        // 112
static constexpr int TOTAL_BLOCKS = OBJ_BLOCKS + TGT_BLOCKS;  // 512

struct Params {
    const float* p[3];
    const float* tbox[3];
    const float* anch[3];
    const int* bb[3];
    const int* aa[3];
    const int* gj[3];
    const int* gi[3];
    const int* tcls[3];
};

__device__ __forceinline__ float softplusf(float x) {
    return fmaxf(x, 0.0f) + log1pf(expf(-fabsf(x)));
}
__device__ __forceinline__ float sigm(float x) { return 1.0f / (1.0f + expf(-x)); }

// acc[blk][4]: obj block -> {objsum, 0, 0, 0}; tgt block -> {0, xtv, boxv, clsv}
// Every block writes its full row, so no zero-init of d_ws is needed.
__global__ __launch_bounds__(256) void crit_main(Params P, double* acc) {
    __shared__ float sh[12];
    const int tid = threadIdx.x;
    const int blk = blockIdx.x;

    if (blk < OBJ_BLOCKS) {
        int lvl, gidL, T, nk;
        if (blk < OB0)            { lvl = 0; gidL = blk * 256 + tid;          T = OB0 * 256; nk = 4; }
        else if (blk < OB0 + OB1) { lvl = 1; gidL = (blk - OB0) * 256 + tid;  T = OB1 * 256; nk = 4; }
        else                      { lvl = 2; gidL = (blk - OB0 - OB1) * 256 + tid; T = OB2 * 256; nk = 3; }
        (void)lvl;
        const float* p = P.p[lvl];
        float x[4];
        #pragma unroll
        for (int k = 0; k < 4; ++k)
            if (k < nk) x[k] = p[(gidL + k * T) * CH + 4];   // 32-bit offsets (max ~26.1M)
        float v = 0.0f;
        #pragma unroll
        for (int k = 0; k < 4; ++k)
            if (k < nk) v += softplusf(x[k]);
        #pragma unroll
        for (int off = 32; off > 0; off >>= 1) v += __shfl_down(v, off, 64);
        if ((tid & 63) == 0) sh[tid >> 6] = v;
        __syncthreads();
        if (tid == 0) {
            double s = (double)sh[0] + (double)sh[1] + (double)sh[2] + (double)sh[3];
            double* row = acc + blk * 4;
            row[0] = s; row[1] = 0.0; row[2] = 0.0; row[3] = 0.0;
        }
    } else {
        // ---- 4 threads per target, 64 targets per block (level-pure blocks)
        const int t = (blk - OBJ_BLOCKS) * 64 + (tid >> 2);  // global target id
        const int j = tid & 3;                               // sub-lane within target
        int lvl, k, g;
        if (t < N0)            { lvl = 0; k = t;            g = G0; }
        else if (t < N0 + N1)  { lvl = 1; k = t - N0;       g = G1; }
        else                   { lvl = 2; k = t - N0 - N1;  g = G2; }

        const int bi = P.bb[lvl][k], ai = P.aa[lvl][k];
        const int gjj = P.gj[lvl][k], gii = P.gi[lvl][k];
        const int tc = P.tcls[lvl][k];
        const float* ps = P.p[lvl] + (((bi * NA_ + ai) * g + gjj) * g + gii) * CH;

        // class BCE partial: 20 contiguous classes per thread
        const int cbase = 5 + j * 20;
        float clsv = 0.0f;
        #pragma unroll 5
        for (int c = 0; c < 20; ++c) clsv += softplusf(ps[cbase + c]);
        if (tc >= j * 20 && tc < j * 20 + 20) clsv -= ps[5 + tc];
        // sum class partials across the aligned 4-lane group
        clsv += __shfl_xor(clsv, 1, 64);
        clsv += __shfl_xor(clsv, 2, 64);

        float boxv = 0.0f, xtv = 0.0f;
        if (j == 0) {
            const float s0 = ps[0], s1 = ps[1], s2 = ps[2], s3 = ps[3], s4 = ps[4];
            const float ax = P.anch[lvl][k * 2 + 0], ay = P.anch[lvl][k * 2 + 1];
            const float tx = P.tbox[lvl][k * 4 + 0], ty = P.tbox[lvl][k * 4 + 1];
            const float tw = P.tbox[lvl][k * 4 + 2], th = P.tbox[lvl][k * 4 + 3];

            const float eps = 1e-7f;
            const float x1 = sigm(s0) * 2.0f - 0.5f;
            const float y1 = sigm(s1) * 2.0f - 0.5f;
            const float swv = sigm(s2) * 2.0f;  const float w1 = swv * swv * ax;
            const float shv = sigm(s3) * 2.0f;  const float h1 = shv * shv * ay;

            const float b1x1 = x1 - w1 * 0.5f, b1x2 = x1 + w1 * 0.5f;
            const float b1y1 = y1 - h1 * 0.5f, b1y2 = y1 + h1 * 0.5f;
            const float b2x1 = tx - tw * 0.5f, b2x2 = tx + tw * 0.5f;
            const float b2y1 = ty - th * 0.5f, b2y2 = ty + th * 0.5f;

            const float iw = fmaxf(fminf(b1x2, b2x2) - fmaxf(b1x1, b2x1), 0.0f);
            const float ih = fmaxf(fminf(b1y2, b2y2) - fmaxf(b1y1, b2y1), 0.0f);
            const float inter = iw * ih;
            const float uni = w1 * h1 + tw * th - inter + eps;
            const float iou = inter / uni;
            const float cw = fmaxf(b1x2, b2x2) - fminf(b1x1, b2x1);
            const float chh = fmaxf(b1y2, b2y2) - fminf(b1y1, b2y1);
            const float c2 = cw * cw + chh * chh + eps;
            const float dx = b2x1 + b2x2 - b1x1 - b1x2;
            const float dy = b2y1 + b2y2 - b1y1 - b1y2;
            const float rho2 = (dx * dx + dy * dy) * 0.25f;
            const float dv = atanf(tw / (th + eps)) - atanf(w1 / (h1 + eps));
            const float v4 = 0.40528473456935109f * dv * dv;   // 4/pi^2
            const float alpha = v4 / (v4 - iou + 1.0f + eps);
            const float ciou = iou - (rho2 / c2 + v4 * alpha);

            boxv = 1.0f - ciou;
            xtv  = s4 * fmaxf(ciou, 0.0f);
        } else {
            clsv = 0.0f;   // only group-lane-0 contributes the (full) class sum
        }

        #pragma unroll
        for (int off = 32; off > 0; off >>= 1) {
            boxv += __shfl_down(boxv, off, 64);
            xtv  += __shfl_down(xtv,  off, 64);
            clsv += __shfl_down(clsv, off, 64);
        }
        const int wid = tid >> 6;
        if ((tid & 63) == 0) { sh[wid * 3 + 0] = boxv; sh[wid * 3 + 1] = xtv; sh[wid * 3 + 2] = clsv; }
        __syncthreads();
        if (tid == 0) {
            double bs = 0, xs = 0, cs = 0;
            #pragma unroll
            for (int w = 0; w < 4; ++w) {
                bs += (double)sh[w * 3 + 0];
                xs += (double)sh[w * 3 + 1];
                cs += (double)sh[w * 3 + 2];
            }
            double* row = acc + blk * 4;
            row[0] = 0.0; row[1] = xs; row[2] = bs; row[3] = cs;
        }
    }
}

// Reduce acc[512][4] -> 12 per-level quantities -> 5 outputs. One block.
__global__ __launch_bounds__(256) void crit_finalize(const double* acc, float* out) {
    __shared__ double sh[4][12];
    const int tid = threadIdx.x;
    double q[12];
    #pragma unroll
    for (int i = 0; i < 12; ++i) q[i] = 0.0;

    #pragma unroll
    for (int r = 0; r < 2; ++r) {
        const int row = tid * 2 + r;   // 0..511
        int lvl;
        if (row < OB0)                        lvl = 0;
        else if (row < OB0 + OB1)             lvl = 1;
        else if (row < OBJ_BLOCKS)            lvl = 2;
        else if (row < OBJ_BLOCKS + 64)       lvl = 0;
        else if (row < OBJ_BLOCKS + 96)       lvl = 1;
        else                                  lvl = 2;
        const double* rp = acc + row * 4;
        #pragma unroll
        for (int i = 0; i < 4; ++i) q[lvl * 4 + i] += rp[i];
    }

    #pragma unroll
    for (int i = 0; i < 12; ++i) {
        #pragma unroll
        for (int off = 32; off > 0; off >>= 1) q[i] += __shfl_down(q[i], off, 64);
    }
    const int wid = tid >> 6;
    if ((tid & 63) == 0) {
        #pragma unroll
        for (int i = 0; i < 12; ++i) sh[wid][i] = q[i];
    }
    __syncthreads();
    if (tid == 0) {
        double qq[12];
        #pragma unroll
        for (int i = 0; i < 12; ++i)
            qq[i] = sh[0][i] + sh[1][i] + sh[2][i] + sh[3][i];
        const double bal[3]   = {4.0, 1.0, 0.4};
        const double ncell[3] = {(double)C0, (double)C1, (double)C2};
        const double nt[3]    = {(double)N0, (double)N1, (double)N2};
        double lbox = 0.0, lobj = 0.0, lcls = 0.0;
        for (int l = 0; l < 3; ++l) {
            lobj += bal[l] * (qq[l * 4 + 0] - qq[l * 4 + 1]) / ncell[l];
            lbox += qq[l * 4 + 2] / nt[l];
            lcls += qq[l * 4 + 3] / (nt[l] * (double)NCLS);
        }
        lbox *= 0.05;   // W_BOX
        lcls *= 0.5;    // W_CLS
        const double loss = lbox + lobj + lcls;
        out[0] = (float)(loss * (double)B_);
        out[1] = (float)lbox;
        out[2] = (float)lobj;
        out[3] = (float)lcls;
        out[4] = (float)loss;
    }
}

extern "C" void kernel_launch(void* const* d_in, const int* in_sizes, int n_in,
                              void* d_out, int out_size, void* d_ws, size_t ws_size,
                              hipStream_t stream) {
    Params P;
    for (int l = 0; l < 3; ++l) {
        void* const* base = d_in + l * 8;  // dict order: p, tbox, anch, b, a, gj, gi, tcls
        P.p[l]    = (const float*)base[0];
        P.tbox[l] = (const float*)base[1];
        P.anch[l] = (const float*)base[2];
        P.bb[l]   = (const int*)base[3];
        P.aa[l]   = (const int*)base[4];
        P.gj[l]   = (const int*)base[5];
        P.gi[l]   = (const int*)base[6];
        P.tcls[l] = (const int*)base[7];
    }
    double* acc = (double*)d_ws;   // 512 * 4 doubles = 16 KB, fully overwritten
    crit_main<<<TOTAL_BLOCKS, 256, 0, stream>>>(P, acc);
    crit_finalize<<<1, 256, 0, stream>>>(acc, (float*)d_out);
}